// Round 6
// baseline (866.003 us; speedup 1.0000x reference)
//
#include <hip/hip_runtime.h>
#include <cmath>

// Problem dims (fixed by setup_inputs)
#define T_    4
#define B_    64
#define N_    196
#define P_    768
#define D_    256
#define BN_   (B_*N_)          // 12544
#define M_    (T_*BN_)         // 50176
#define SITES (BN_*D_)         // 3211264

#define BM    128              // block tile m
#define BN2   64               // block tile d
#define TK    16
#define KITER (P_/TK)          // 48
#define GBLKS ((M_/BM)*(D_/BN2))   // 392*4 = 1568
#define ALEN  194              // 32 groups*6+2 f32x2 (1552B row: +16B bank shift/row)
#define BLEN  98               // 16 groups*6+2 f32x2 (784B row)

typedef __attribute__((ext_vector_type(2))) float f32x2;

// pk mul+add with TIED accumulator: 2 VALU instrs, no copies. v_pk_* are two
// independent correctly-rounded IEEE f32 ops (no fusion) -> bit-identical to
// the scalar __fmul_rn/__fadd_rn sequence.
__device__ __forceinline__ void pk_fma(f32x2& acc, f32x2 a, f32x2 b) {
    f32x2 t;
    asm("v_pk_mul_f32 %1, %2, %3\n\t"
        "v_pk_add_f32 %0, %0, %1"
        : "+v"(acc), "=&v"(t) : "v"(a), "v"(b));
}

// ---------------------------------------------------------------------------
// Kernel 1: numpy c_einsum f32 emulation (SSE 4-lane semantics).
// lane j = sequential f32 sum over p≡j mod 4 of fl32(x*w); combine
// (l0+l1)+(l2+l3). Per-output p-order unchanged by tiling.
// 8m x 4d register tile (acc = 64 f32x2 = 128 VGPR): LDS-read instrs per
// pk-op drop 25% vs 4x4 (6 b128 per 64 pk), loop overhead halves per pk.
// Grouped LDS layout (4-elem groups, stride 6 f32x2): conflict-free b128
// reads (A: 4 distinct addrs/wave broadcast; B: 48B stride -> 2-way, free).
// Double-buffered, one barrier per k-step. Epilogue writes h and hT.
// XCD swizzle: bid%8 = XCD owns 49 consecutive m-tiles x 4 d-tiles.
// ---------------------------------------------------------------------------
extern "C" __global__ __launch_bounds__(256)
void gemm_f32emu(const float* __restrict__ x, const float* __restrict__ w,
                 float* __restrict__ h, float* __restrict__ hT) {
    __shared__ __align__(16) f32x2 As2[2][TK/2][ALEN];   // 24.25 KB
    __shared__ __align__(16) f32x2 Bs2[2][TK/2][BLEN];   // 12.25 KB

    const int tid = threadIdx.x;
    const int tx  = tid & 15;        // d-group (4 d)
    const int ty  = tid >> 4;        // m-group (8 m)
    const int bid = blockIdx.x;      // 0..1567
    const int xcd = bid & 7;
    const int lin = bid >> 3;        // 0..195
    const int m0  = (xcd * 49 + (lin >> 2)) * BM;
    const int d0  = (lin & 3) * BN2;

    // staging coords: A = 128 rows x 16 p (2 float4/thread), B = 64 x 16 (1)
    const int ar = tid >> 1;                 // A row 0..127
    const int sa = (tid & 1) * 8;            // A p-offset 0 or 8
    const int ra = (tid & 1) * 4;            // first kp row of this thread's A quads
    const int ga = (ar >> 2) * 6 + (ar & 3); // grouped store offset
    const int br = tid >> 2;                 // B row 0..63
    const int qb = tid & 3;                  // B p-quad
    const int gb = (br >> 2) * 6 + (br & 3);

    const float* xp = x + (size_t)(m0 + ar) * P_ + sa;
    const float* wp = w + (size_t)(d0 + br) * P_ + qb * 4;

    f32x2 acc[8][4][2];
#pragma unroll
    for (int i = 0; i < 8; ++i)
#pragma unroll
        for (int j = 0; j < 4; ++j)
#pragma unroll
            for (int p = 0; p < 2; ++p) acc[i][j][p] = f32x2{0.0f, 0.0f};

    // prologue: stage tile 0
    {
        const float4 va0 = *(const float4*)(xp);
        const float4 va1 = *(const float4*)(xp + 4);
        const float4 vb  = *(const float4*)(wp);
        As2[0][ra + 0][ga] = f32x2{va0.x, va0.y};
        As2[0][ra + 1][ga] = f32x2{va0.z, va0.w};
        As2[0][ra + 2][ga] = f32x2{va1.x, va1.y};
        As2[0][ra + 3][ga] = f32x2{va1.z, va1.w};
        Bs2[0][qb * 2 + 0][gb] = f32x2{vb.x, vb.y};
        Bs2[0][qb * 2 + 1][gb] = f32x2{vb.z, vb.w};
    }

    int cur = 0;
    for (int k0 = 0; k0 < KITER; ++k0) {
        __syncthreads();
        float4 va0, va1, vb;
        const bool have = (k0 + 1 < KITER);
        if (have) {
            va0 = *(const float4*)(xp + (k0 + 1) * TK);
            va1 = *(const float4*)(xp + (k0 + 1) * TK + 4);
            vb  = *(const float4*)(wp + (k0 + 1) * TK);
        }
#pragma unroll
        for (int kp = 0; kp < TK / 2; ++kp) {
            const int pi = kp & 1;   // kp even -> SSE lanes (0,1); odd -> (2,3)
            const f32x2* Ar = As2[cur][kp];
            const f32x2* Br = Bs2[cur][kp];
            const float4 A0 = *(const float4*)(Ar + ty * 12);
            const float4 A1 = *(const float4*)(Ar + ty * 12 + 2);
            const float4 A2 = *(const float4*)(Ar + ty * 12 + 6);
            const float4 A3 = *(const float4*)(Ar + ty * 12 + 8);
            const float4 B0 = *(const float4*)(Br + tx * 6);
            const float4 B1 = *(const float4*)(Br + tx * 6 + 2);
            f32x2 af[8], bf[4];
            af[0] = f32x2{A0.x, A0.y}; af[1] = f32x2{A0.z, A0.w};
            af[2] = f32x2{A1.x, A1.y}; af[3] = f32x2{A1.z, A1.w};
            af[4] = f32x2{A2.x, A2.y}; af[5] = f32x2{A2.z, A2.w};
            af[6] = f32x2{A3.x, A3.y}; af[7] = f32x2{A3.z, A3.w};
            bf[0] = f32x2{B0.x, B0.y}; bf[1] = f32x2{B0.z, B0.w};
            bf[2] = f32x2{B1.x, B1.y}; bf[3] = f32x2{B1.z, B1.w};
#pragma unroll
            for (int i = 0; i < 8; ++i)
#pragma unroll
                for (int j = 0; j < 4; ++j)
                    pk_fma(acc[i][j][pi], af[i], bf[j]);
        }
        if (have) {
            As2[cur ^ 1][ra + 0][ga] = f32x2{va0.x, va0.y};
            As2[cur ^ 1][ra + 1][ga] = f32x2{va0.z, va0.w};
            As2[cur ^ 1][ra + 2][ga] = f32x2{va1.x, va1.y};
            As2[cur ^ 1][ra + 3][ga] = f32x2{va1.z, va1.w};
            Bs2[cur ^ 1][qb * 2 + 0][gb] = f32x2{vb.x, vb.y};
            Bs2[cur ^ 1][qb * 2 + 1][gb] = f32x2{vb.z, vb.w};
        }
        cur ^= 1;
    }

    // epilogue: SSE lane combine, write h[m][d] and (optionally) hT[d][m]
    float res[8][4];
#pragma unroll
    for (int i = 0; i < 8; ++i)
#pragma unroll
        for (int j = 0; j < 4; ++j) {
            const float l01 = __fadd_rn(acc[i][j][0].x, acc[i][j][0].y);
            const float l23 = __fadd_rn(acc[i][j][1].x, acc[i][j][1].y);
            res[i][j] = __fadd_rn(l01, l23);
        }
#pragma unroll
    for (int i = 0; i < 8; ++i) {
        float4 o = {res[i][0], res[i][1], res[i][2], res[i][3]};
        *(float4*)(h + (size_t)(m0 + ty * 8 + i) * D_ + d0 + tx * 4) = o;
    }
    if (hT) {
#pragma unroll
        for (int j = 0; j < 4; ++j) {
            float4 o0 = {res[0][j], res[1][j], res[2][j], res[3][j]};
            float4 o1 = {res[4][j], res[5][j], res[6][j], res[7][j]};
            float* col = hT + (size_t)(d0 + tx * 4 + j) * M_ + m0 + ty * 8;
            *(float4*)(col)     = o0;
            *(float4*)(col + 4) = o1;
        }
    }
}

// ---------------------------------------------------------------------------
// Kernel 2 (hT path): FUSED mean+var per channel d (one block each).
// Phase 1: fully SEQUENTIAL f32 mean chain over m (exact numpy order);
// 255 threads double-buffer the contiguous column in LDS, tid0 chains with
// register ping-pong (32-add groups cover LDS latency).
// Phase 2: var — per (t,b): f64 interior with EXACT lane-strided partials +
// shuffle tree; f32 join chain replayed serially; inv = 1/sqrt(var+eps).
// ---------------------------------------------------------------------------
#define MCH2 7168                    // 7 chunks * 7168 = 50176
#define GRP  224                     // 32-float groups per chunk
extern "C" __global__ __launch_bounds__(256)
void meanvar_hT(const float* __restrict__ hT, float* __restrict__ mean_,
                float* __restrict__ inv_) {
    __shared__ float buf[2][MCH2];   // 56 KB
    __shared__ float chunks[256];
    __shared__ float mn_sh;
    const int tid = threadIdx.x;
    const int d   = blockIdx.x;
    const float* src = hT + (size_t)d * M_;

    // ---- phase 1: mean ----
#pragma unroll
    for (int u = 0; u < 7; ++u)
        *(float4*)&buf[0][(u * 256 + tid) * 4] =
            *(const float4*)&src[(u * 256 + tid) * 4];
    __syncthreads();

    float acc = 0.0f;
    for (int c = 0; c < 7; ++c) {
        const int cb = c & 1;
        const bool have = (c + 1 < 7);
        float4 v[7];
        if (have) {
            const float* rp = src + (c + 1) * MCH2;
#pragma unroll
            for (int u = 0; u < 7; ++u)
                v[u] = *(const float4*)&rp[(u * 256 + tid) * 4];
        }
        if (tid == 0) {
            const float4* bp = (const float4*)buf[cb];
            float4 p0[8], p1[8];
#pragma unroll
            for (int u = 0; u < 8; ++u) p0[u] = bp[u];
            for (int gp = 0; gp < GRP; gp += 2) {
#pragma unroll
                for (int u = 0; u < 8; ++u) p1[u] = bp[(gp + 1) * 8 + u];
#pragma unroll
                for (int u = 0; u < 8; ++u) {
                    acc = __fadd_rn(acc, p0[u].x);
                    acc = __fadd_rn(acc, p0[u].y);
                    acc = __fadd_rn(acc, p0[u].z);
                    acc = __fadd_rn(acc, p0[u].w);
                }
                const int g2 = (gp + 2 < GRP) ? gp + 2 : 0;   // guarded wrap
#pragma unroll
                for (int u = 0; u < 8; ++u) p0[u] = bp[g2 * 8 + u];
#pragma unroll
                for (int u = 0; u < 8; ++u) {
                    acc = __fadd_rn(acc, p1[u].x);
                    acc = __fadd_rn(acc, p1[u].y);
                    acc = __fadd_rn(acc, p1[u].z);
                    acc = __fadd_rn(acc, p1[u].w);
                }
            }
        }
        if (have) {
#pragma unroll
            for (int u = 0; u < 7; ++u)
                *(float4*)&buf[cb ^ 1][(u * 256 + tid) * 4] = v[u];
        }
        __syncthreads();
    }
    if (tid == 0) {
        const float mn = __fdiv_rn(acc, 50176.0f);
        mean_[d] = mn;
        mn_sh = mn;
    }
    __syncthreads();

    // ---- phase 2: var ----
    const float mn = mn_sh;
    const int wv   = tid >> 6;
    const int lane = tid & 63;
    for (int tb = wv; tb < T_ * B_; tb += 4) {
        double part = 0.0;
        for (int n = lane; n < N_; n += 64) {
            const float hv = src[tb * N_ + n];
            const float t1 = __fsub_rn(hv, mn);
            const float sq = __fmul_rn(t1, t1);
            part += (double)sq;
        }
#pragma unroll
        for (int off = 32; off; off >>= 1) part += __shfl_down(part, off);
        if (lane == 0) chunks[tb] = (float)part;
    }
    __syncthreads();
    if (tid == 0) {
        float accf = 0.0f;
        for (int tb = 0; tb < T_ * B_; ++tb) accf = __fadd_rn(accf, chunks[tb]);
        const float var = __fdiv_rn(accf, 50176.0f);
        inv_[d] = __fdiv_rn(1.0f, __fsqrt_rn(__fadd_rn(var, 1e-5f)));
    }
}

// ---------------------------------------------------------------------------
// Fallback kernels (small workspace): read h[m][d] directly.
// ---------------------------------------------------------------------------
#define MCH  256
#define DCH  16
#define PADW 20
#define NCHK (M_/MCH)

extern "C" __global__ __launch_bounds__(256)
void mean_seq(const float* __restrict__ h, float* __restrict__ mean_) {
    __shared__ __align__(16) float buf[2][MCH][PADW];
    const int tid = threadIdx.x;
    const int d0  = blockIdx.x * DCH;
    {
        const float* rp = h + (size_t)tid * D_ + d0;
        *(float4*)&buf[0][tid][0]  = *(const float4*)(rp + 0);
        *(float4*)&buf[0][tid][4]  = *(const float4*)(rp + 4);
        *(float4*)&buf[0][tid][8]  = *(const float4*)(rp + 8);
        *(float4*)&buf[0][tid][12] = *(const float4*)(rp + 12);
    }
    __syncthreads();
    float acc = 0.0f;
    for (int c = 0; c < NCHK; ++c) {
        const int cb = c & 1;
        const bool have = (c + 1 < NCHK);
        float4 v0, v1, v2, v3;
        if (have) {
            const float* rp = h + ((size_t)(c + 1) * MCH + tid) * D_ + d0;
            v0 = *(const float4*)(rp + 0);
            v1 = *(const float4*)(rp + 4);
            v2 = *(const float4*)(rp + 8);
            v3 = *(const float4*)(rp + 12);
        }
        if (tid < DCH) {
#pragma unroll 16
            for (int m = 0; m < MCH; ++m)
                acc = __fadd_rn(acc, buf[cb][m][tid]);
        }
        if (have) {
            *(float4*)&buf[cb ^ 1][tid][0]  = v0;
            *(float4*)&buf[cb ^ 1][tid][4]  = v1;
            *(float4*)&buf[cb ^ 1][tid][8]  = v2;
            *(float4*)&buf[cb ^ 1][tid][12] = v3;
        }
        __syncthreads();
    }
    if (tid < DCH) mean_[d0 + tid] = __fdiv_rn(acc, 50176.0f);
}

extern "C" __global__ __launch_bounds__(64)
void var_seq(const float* __restrict__ h, const float* __restrict__ mean_,
             float* __restrict__ inv_) {
    const int d    = blockIdx.x;
    const int lane = threadIdx.x;
    const float mn = mean_[d];
    float accf = 0.0f;
    for (int tb = 0; tb < T_ * B_; ++tb) {
        double part = 0.0;
        for (int n = lane; n < N_; n += 64) {
            const float hv = h[((size_t)tb * N_ + n) * D_ + d];
            const float t1 = __fsub_rn(hv, mn);
            const float sq = __fmul_rn(t1, t1);
            part += (double)sq;
        }
#pragma unroll
        for (int off = 32; off; off >>= 1) part += __shfl_down(part, off);
        accf = __fadd_rn(accf, (float)part);
    }
    if (lane == 0) {
        const float var = __fdiv_rn(accf, 50176.0f);
        inv_[d] = __fdiv_rn(1.0f, __fsqrt_rn(__fadd_rn(var, 1e-5f)));
    }
}

// ---------------------------------------------------------------------------
// pe table — identical f64 expressions as the inline path.
// ---------------------------------------------------------------------------
extern "C" __global__ __launch_bounds__(256)
void pe_build(float* __restrict__ pe_) {
    const int d = threadIdx.x;
    const int n = blockIdx.x;
    const double dv  = exp((double)(d & ~1) * (-9.210340371976184 / 256.0));
    const double arg = ((double)n * dv) * (256.0 / 196.0);
    pe_[(size_t)n * D_ + d] = (d & 1) ? (float)cos(arg) : (float)sin(arg);
}

// ---------------------------------------------------------------------------
// Kernel 4: BN-apply + LIF1 + tAPE + LIF2, exact numpy-f32 op order.
// ---------------------------------------------------------------------------
extern "C" __global__ __launch_bounds__(256)
void lif_final(float* __restrict__ out, const float* __restrict__ mean_,
               const float* __restrict__ inv_, const float* __restrict__ gamma,
               const float* __restrict__ beta, const float* __restrict__ pe_tab) {
    const int idx = blockIdx.x * 256 + threadIdx.x;   // (bn, d)
    const int d = idx & (D_ - 1);
    const int n = (idx >> 8) % N_;

    const float mn = mean_[d];
    const float iv = inv_[d];
    const float g  = gamma[d];
    const float b  = beta[d];

    float pe;
    if (pe_tab) {
        pe = pe_tab[(size_t)n * D_ + d];
    } else {
        const double dv  = exp((double)(d & ~1) * (-9.210340371976184 / 256.0));
        const double arg = ((double)n * dv) * (256.0 / 196.0);
        pe = (d & 1) ? (float)cos(arg) : (float)sin(arg);
    }

    float hv[4];
#pragma unroll
    for (int t = 0; t < T_; ++t) hv[t] = out[(size_t)t * SITES + idx];

    float v1 = 0.0f, v2 = 0.0f, s2v[4];
#pragma unroll
    for (int t = 0; t < T_; ++t) {
        const float t1 = __fsub_rn(hv[t], mn);
        const float u  = __fmul_rn(t1, iv);
        const float hb = __fadd_rn(__fmul_rn(u, g), b);
        v1 = __fadd_rn(v1, __fmul_rn(__fsub_rn(hb, v1), 0.5f));
        const float s1 = (v1 >= 0.5f) ? 1.0f : 0.0f;
        v1 = __fmul_rn(v1, __fsub_rn(1.0f, s1));
        const float y = __fadd_rn(s1, pe);
        v2 = __fadd_rn(v2, __fmul_rn(__fsub_rn(y, v2), 0.5f));
        const float s2 = (v2 >= 0.5f) ? 1.0f : 0.0f;
        v2 = __fmul_rn(v2, __fsub_rn(1.0f, s2));
        s2v[t] = s2;
    }
#pragma unroll
    for (int t = 0; t < T_; ++t) out[(size_t)t * SITES + idx] = s2v[t];
}

extern "C" void kernel_launch(void* const* d_in, const int* in_sizes, int n_in,
                              void* d_out, int out_size, void* d_ws, size_t ws_size,
                              hipStream_t stream) {
    const float* x     = (const float*)d_in[0];
    const float* w     = (const float*)d_in[1];
    const float* gamma = (const float*)d_in[2];
    const float* beta  = (const float*)d_in[3];
    float* out = (float*)d_out;

    float* mean_ = (float*)d_ws;              // 256
    float* inv_  = mean_ + D_;                // 256
    float* pe_   = inv_  + D_;                // 196*256
    float* hT_   = pe_   + (size_t)N_ * D_;   // 50176*256 (51.4 MB)

    const size_t need_pe = (size_t)(2 * D_ + N_ * D_) * sizeof(float);
    const size_t need_hT = need_pe + (size_t)M_ * D_ * sizeof(float);
    const bool use_pe = ws_size >= need_pe;
    const bool use_hT = ws_size >= need_hT;

    gemm_f32emu<<<GBLKS, 256, 0, stream>>>(x, w, out, use_hT ? hT_ : nullptr);
    if (use_hT) {
        meanvar_hT<<<D_, 256, 0, stream>>>(hT_, mean_, inv_);
    } else {
        mean_seq<<<16, 256, 0, stream>>>(out, mean_);
        var_seq<<<D_, 64, 0, stream>>>(out, mean_, inv_);
    }
    if (use_pe) pe_build<<<N_, 256, 0, stream>>>(pe_);
    lif_final<<<SITES / 256, 256, 0, stream>>>(out, mean_, inv_, gamma, beta,
                                               use_pe ? pe_ : nullptr);
}